// Round 8
// baseline (360.788 us; speedup 1.0000x reference)
//
#include <hip/hip_runtime.h>

// instant-NGP hash-grid encoder, 12 levels, F=2, N = 1<<20 points.
// Levels 0-4 dense (R^3 <= 2^19), levels 5-11 hashed (table = 2^19 entries = 4 MB).
//
// R2: per-hashed-level passes (gridDim.y) + ws staging + merge kernel.
// R4/R6: corner pairing (dx=0/1 in one 16B load) — win in both kernels.
// R5 lesson: no NT hints — ws/x are re-read by the next kernel.
// R7 lesson: 2 pts/thread hurt (compiler serialized at VGPR=20; waves halved).
// R8: branch-free hashed path. Mixed even/odd-ix waves serialized two gather
//     latency exposures under divergence. Now every corner pair does two
//     aligned 16B pair-loads (a0's pair and a1's pair) + lane selects —
//     uniform control flow, all 8 loads issue together. Even-ix lanes load
//     the same pair twice (L1 same-line hit).

#define N_LEVELS 12
#define N_HASHED 7

typedef float f4a16 __attribute__((ext_vector_type(4), aligned(16)));
typedef float f4a8  __attribute__((ext_vector_type(4), aligned(8)));

__device__ __forceinline__ void trilinear_setup(float p, int r, float* w, unsigned* i0)
{
    float f  = p * (float)(r - 1);
    float f0 = fminf(fmaxf(floorf(f), 0.0f), (float)(r - 2));
    float w1 = f - f0;
    w[0] = 1.0f - w1;
    w[1] = w1;
    *i0 = (unsigned)f0;
}

// ---------------- pass 1: hashed levels (5..11), one level per blockIdx.y ----
__global__ __launch_bounds__(256) void hashed_levels_kernel(
    const float* __restrict__ x,
    const float* __restrict__ params,
    float2* __restrict__ ws,   // [N_HASHED][N]
    int N)
{
    constexpr int      HRES[N_HASHED] = {92, 128, 184, 256, 368, 512, 736};
    constexpr unsigned HOFF[N_HASHED] = {408512u, 932800u, 1457088u, 1981376u,
                                         2505664u, 3029952u, 3554240u};
    constexpr unsigned HASH_MASK = 524287u;   // 2^19 - 1
    constexpr unsigned P1 = 2654435761u;
    constexpr unsigned P2 = 805459861u;

    const int n = blockIdx.x * blockDim.x + threadIdx.x;
    if (n >= N) return;
    const int li = blockIdx.y;          // 0..6 -> level 5+li

    const float px = x[3 * n + 0];
    const float py = x[3 * n + 1];
    const float pz = x[3 * n + 2];

    const int r = HRES[li];
    float wx[2], wy[2], wz[2];
    unsigned ix, iy, iz;
    trilinear_setup(px, r, wx, &ix);
    trilinear_setup(py, r, wy, &iy);
    trilinear_setup(pz, r, wz, &iz);

    const float* __restrict__ tabf = params + 2u * (size_t)HOFF[li];

    const unsigned hy[2] = {iy * P1, (iy + 1u) * P1};
    const unsigned hz[2] = {iz * P2, (iz + 1u) * P2};

    // Branch-free: for each of the 4 (dy,dz) combos, load the aligned 16B
    // pair containing corner dx=0 (a0) and the one containing dx=1 (a1).
    // All 8 loads are independent -> one latency exposure.
    unsigned a0[4], a1[4];
#pragma unroll
    for (int p = 0; p < 4; ++p) {
        const unsigned dy = p & 1, dz = (p >> 1) & 1;
        const unsigned h = hy[dy] ^ hz[dz];
        a0[p] = (ix ^ h) & HASH_MASK;
        a1[p] = ((ix + 1u) ^ h) & HASH_MASK;
    }

    f4a16 q0[4], q1[4];
#pragma unroll
    for (int p = 0; p < 4; ++p) {
        q0[p] = *(const f4a16*)(tabf + 2u * (a0[p] & ~1u));
        q1[p] = *(const f4a16*)(tabf + 2u * (a1[p] & ~1u));
    }

    float s0 = 0.0f, s1 = 0.0f;
#pragma unroll
    for (int p = 0; p < 4; ++p) {
        const unsigned dy = p & 1, dz = (p >> 1) & 1;
        const bool o0 = (a0[p] & 1u) != 0u;
        const bool o1 = (a1[p] & 1u) != 0u;
        const float c0x = o0 ? q0[p].z : q0[p].x;
        const float c0y = o0 ? q0[p].w : q0[p].y;
        const float c1x = o1 ? q1[p].z : q1[p].x;
        const float c1y = o1 ? q1[p].w : q1[p].y;
        const float wyz = wy[dy] * wz[dz];
        const float wc0 = wx[0] * wyz;
        const float wc1 = wx[1] * wyz;
        s0 = fmaf(wc0, c0x, s0);
        s1 = fmaf(wc0, c0y, s1);
        s0 = fmaf(wc1, c1x, s0);
        s1 = fmaf(wc1, c1y, s1);
    }

    ws[(size_t)li * N + n] = make_float2(s0, s1);
}

// ---------------- pass 2: dense levels (0..4) + merge (R6 known-good) -------
__global__ __launch_bounds__(256) void dense_merge_kernel(
    const float* __restrict__ x,
    const float* __restrict__ params,
    const float2* __restrict__ ws,   // [N_HASHED][N]
    float* __restrict__ out,
    int N)
{
    constexpr int      DRES[5] = {16, 23, 32, 46, 64};
    constexpr unsigned DOFF[5] = {0u, 4096u, 16264u, 49032u, 146368u};

    const int n = blockIdx.x * blockDim.x + threadIdx.x;
    if (n >= N) return;

    const float px = x[3 * n + 0];
    const float py = x[3 * n + 1];
    const float pz = x[3 * n + 2];

    float res[2 * N_LEVELS];

#pragma unroll
    for (int l = 0; l < 5; ++l) {
        const int r = DRES[l];
        float wx[2], wy[2], wz[2];
        unsigned ix, iy, iz;
        trilinear_setup(px, r, wx, &ix);
        trilinear_setup(py, r, wy, &iy);
        trilinear_setup(pz, r, wz, &iz);

        const float* __restrict__ tabf = params + 2u * (size_t)DOFF[l];
        const unsigned rr = (unsigned)(r * r);
        const unsigned base = ix + iy * (unsigned)r + iz * rr;

        float s0 = 0.0f, s1 = 0.0f;
#pragma unroll
        for (int p = 0; p < 4; ++p) {
            const unsigned dy = p & 1, dz = (p >> 1) & 1;
            const unsigned idx = base + dy * (unsigned)r + dz * rr;  // dx=0; dx=1 is idx+1
            const f4a8 q = *(const f4a8*)(tabf + 2u * idx);          // {c0.x,c0.y,c1.x,c1.y}
            const float wyz = wy[dy] * wz[dz];
            const float wc0 = wx[0] * wyz;
            const float wc1 = wx[1] * wyz;
            s0 = fmaf(wc0, q.x, s0);
            s1 = fmaf(wc0, q.y, s1);
            s0 = fmaf(wc1, q.z, s0);
            s1 = fmaf(wc1, q.w, s1);
        }
        res[2 * l + 0] = s0;
        res[2 * l + 1] = s1;
    }

#pragma unroll
    for (int li = 0; li < N_HASHED; ++li) {
        float2 f = ws[(size_t)li * N + n];    // coalesced: stride-8B in n
        res[2 * (5 + li) + 0] = f.x;
        res[2 * (5 + li) + 1] = f.y;
    }

    float4* __restrict__ o4 = (float4*)(out + (size_t)n * 24);
#pragma unroll
    for (int k = 0; k < 6; ++k) {
        float4 v;
        v.x = res[4 * k + 0];
        v.y = res[4 * k + 1];
        v.z = res[4 * k + 2];
        v.w = res[4 * k + 3];
        o4[k] = v;
    }
}

// ---------------- fallback: fused single kernel -----------------------------
__global__ __launch_bounds__(256) void grid_encode_fused_kernel(
    const float* __restrict__ x,
    const float* __restrict__ params,
    float* __restrict__ out,
    int N)
{
    int n = blockIdx.x * blockDim.x + threadIdx.x;
    if (n >= N) return;

    const float px = x[3 * n + 0];
    const float py = x[3 * n + 1];
    const float pz = x[3 * n + 2];

    constexpr int   RES[N_LEVELS]    = {16, 23, 32, 46, 64, 92, 128, 184, 256, 368, 512, 736};
    constexpr unsigned OFF[N_LEVELS] = {0u, 4096u, 16264u, 49032u, 146368u, 408512u,
                                        932800u, 1457088u, 1981376u, 2505664u, 3029952u, 3554240u};
    constexpr unsigned HASH_MASK = 524287u;
    constexpr unsigned P1 = 2654435761u;
    constexpr unsigned P2 = 805459861u;

    float res[2 * N_LEVELS];

#pragma unroll
    for (int l = 0; l < N_LEVELS; ++l) {
        const int r = RES[l];
        float wx[2], wy[2], wz[2];
        unsigned ix, iy, iz;
        trilinear_setup(px, r, wx, &ix);
        trilinear_setup(py, r, wy, &iy);
        trilinear_setup(pz, r, wz, &iz);

        const float2* __restrict__ tab = (const float2*)params + OFF[l];
        float s0 = 0.0f, s1 = 0.0f;

        const bool dense = ((long long)r * r * r) <= (long long)524288;
        if (dense) {
            const unsigned rr = (unsigned)(r * r);
            const unsigned base = ix + iy * (unsigned)r + iz * rr;
#pragma unroll
            for (int c = 0; c < 8; ++c) {
                const unsigned dx = c & 1, dy = (c >> 1) & 1, dz = (c >> 2) & 1;
                const unsigned idx = base + dx + dy * (unsigned)r + dz * rr;
                float2 f = tab[idx];
                float wc = (wx[dx] * wy[dy]) * wz[dz];
                s0 = fmaf(wc, f.x, s0);
                s1 = fmaf(wc, f.y, s1);
            }
        } else {
            const unsigned hx[2] = {ix, ix + 1u};
            const unsigned hy[2] = {iy * P1, (iy + 1u) * P1};
            const unsigned hz[2] = {iz * P2, (iz + 1u) * P2};
#pragma unroll
            for (int c = 0; c < 8; ++c) {
                const unsigned dx = c & 1, dy = (c >> 1) & 1, dz = (c >> 2) & 1;
                const unsigned idx = (hx[dx] ^ hy[dy] ^ hz[dz]) & HASH_MASK;
                float2 f = tab[idx];
                float wc = (wx[dx] * wy[dy]) * wz[dz];
                s0 = fmaf(wc, f.x, s0);
                s1 = fmaf(wc, f.y, s1);
            }
        }
        res[2 * l + 0] = s0;
        res[2 * l + 1] = s1;
    }

    float4* __restrict__ o4 = (float4*)(out + (size_t)n * 24);
#pragma unroll
    for (int k = 0; k < 6; ++k) {
        float4 v;
        v.x = res[4 * k + 0];
        v.y = res[4 * k + 1];
        v.z = res[4 * k + 2];
        v.w = res[4 * k + 3];
        o4[k] = v;
    }
}

extern "C" void kernel_launch(void* const* d_in, const int* in_sizes, int n_in,
                              void* d_out, int out_size, void* d_ws, size_t ws_size,
                              hipStream_t stream) {
    const float* x      = (const float*)d_in[0];
    const float* params = (const float*)d_in[1];
    float* out          = (float*)d_out;

    const int N = in_sizes[0] / 3;  // 1<<20
    const int block = 256;
    const int gx = (N + block - 1) / block;

    const size_t ws_needed = (size_t)N_HASHED * (size_t)N * sizeof(float2);  // 56 MB

    if (ws_size >= ws_needed) {
        float2* ws = (float2*)d_ws;
        dim3 grid1(gx, N_HASHED, 1);
        hashed_levels_kernel<<<grid1, block, 0, stream>>>(x, params, ws, N);
        dense_merge_kernel<<<gx, block, 0, stream>>>(x, params, ws, out, N);
    } else {
        grid_encode_fused_kernel<<<gx, block, 0, stream>>>(x, params, out, N);
    }
}

// Round 9
// 319.854 us; speedup vs baseline: 1.1280x; 1.1280x over previous
//
#include <hip/hip_runtime.h>

// instant-NGP hash-grid encoder, 12 levels, F=2, N = 1<<20 points.
// Levels 0-4 dense (R^3 <= 2^19), levels 5-11 hashed (table = 2^19 entries = 4 MB).
//
// R2: per-hashed-level passes (gridDim.y) + ws staging + merge kernel.
// R4/R6: corner pairing (dx=0/1 in one 16B load) — win in both kernels.
// R5 lesson: no NT hints on buffers that are RE-READ (ws, x).
// R7 lesson: 2 pts/thread hurt (waves halved, no MLP gain).
// R8 lesson: branch-free 8x16B loads hurt (258 us) — the hashed pass is
//     line-request-throughput bound; R6's divergent pairing (avg 6 lines/
//     point-level) is the line-count minimum. Reverted to R6 exactly.
// R9: (a) ws stored as fp16 half2 — values |v|<=1e-4, fp16 err ~3e-8 << 2e-6
//     threshold; halves ws traffic. (b) NT store for `out` only (write-once,
//     never re-read) so the 96 MB out stream doesn't evict dense tables/ws
//     from L2 in the merge kernel.

#define N_LEVELS 12
#define N_HASHED 7

typedef float    f4a16 __attribute__((ext_vector_type(4), aligned(16)));
typedef float    f4a8  __attribute__((ext_vector_type(4), aligned(8)));
typedef float    f4v   __attribute__((ext_vector_type(4)));
typedef _Float16 h2v   __attribute__((ext_vector_type(2)));

__device__ __forceinline__ void trilinear_setup(float p, int r, float* w, unsigned* i0)
{
    float f  = p * (float)(r - 1);
    float f0 = fminf(fmaxf(floorf(f), 0.0f), (float)(r - 2));
    float w1 = f - f0;
    w[0] = 1.0f - w1;
    w[1] = w1;
    *i0 = (unsigned)f0;
}

// ---------------- pass 1: hashed levels (5..11), one level per blockIdx.y ----
__global__ __launch_bounds__(256) void hashed_levels_kernel(
    const float* __restrict__ x,
    const float* __restrict__ params,
    _Float16* __restrict__ ws,   // [N_HASHED][N] half2
    int N)
{
    constexpr int      HRES[N_HASHED] = {92, 128, 184, 256, 368, 512, 736};
    constexpr unsigned HOFF[N_HASHED] = {408512u, 932800u, 1457088u, 1981376u,
                                         2505664u, 3029952u, 3554240u};
    constexpr unsigned HASH_MASK = 524287u;   // 2^19 - 1
    constexpr unsigned P1 = 2654435761u;
    constexpr unsigned P2 = 805459861u;

    const int n = blockIdx.x * blockDim.x + threadIdx.x;
    if (n >= N) return;
    const int li = blockIdx.y;          // 0..6 -> level 5+li

    const float px = x[3 * n + 0];
    const float py = x[3 * n + 1];
    const float pz = x[3 * n + 2];

    const int r = HRES[li];
    float wx[2], wy[2], wz[2];
    unsigned ix, iy, iz;
    trilinear_setup(px, r, wx, &ix);
    trilinear_setup(py, r, wy, &iy);
    trilinear_setup(pz, r, wz, &iz);

    const float* __restrict__ tabf = params + 2u * (size_t)HOFF[li];

    const unsigned hy[2] = {iy * P1, (iy + 1u) * P1};
    const unsigned hz[2] = {iz * P2, (iz + 1u) * P2};

    float s0 = 0.0f, s1 = 0.0f;

    if ((ix & 1u) == 0u) {
        // even ix: corner pair (dx=0,dx=1) = {a, a^1} -> one aligned float4
#pragma unroll
        for (int p = 0; p < 4; ++p) {
            const unsigned dy = p & 1, dz = (p >> 1) & 1;
            const unsigned h = hy[dy] ^ hz[dz];
            const unsigned a = (ix ^ h) & HASH_MASK;      // corner dx=0
            const unsigned sw = a & 1u;                   // 1 -> pair stored (c1,c0)
            const f4a16 q = *(const f4a16*)(tabf + 2u * (a & ~1u));
            const float f0x = sw ? q.z : q.x;
            const float f0y = sw ? q.w : q.y;
            const float f1x = sw ? q.x : q.z;
            const float f1y = sw ? q.y : q.w;
            const float wyz = wy[dy] * wz[dz];
            const float wc0 = wx[0] * wyz;
            const float wc1 = wx[1] * wyz;
            s0 = fmaf(wc0, f0x, s0);
            s1 = fmaf(wc0, f0y, s1);
            s0 = fmaf(wc1, f1x, s0);
            s1 = fmaf(wc1, f1y, s1);
        }
    } else {
        const unsigned hx[2] = {ix, ix + 1u};
#pragma unroll
        for (int c = 0; c < 8; ++c) {
            const unsigned dx = c & 1, dy = (c >> 1) & 1, dz = (c >> 2) & 1;
            const unsigned idx = (hx[dx] ^ hy[dy] ^ hz[dz]) & HASH_MASK;
            const float2 f = *(const float2*)(tabf + 2u * idx);
            const float wc = (wx[dx] * wy[dy]) * wz[dz];
            s0 = fmaf(wc, f.x, s0);
            s1 = fmaf(wc, f.y, s1);
        }
    }

    h2v v;
    v.x = (_Float16)s0;
    v.y = (_Float16)s1;
    *(h2v*)(ws + 2u * ((size_t)li * N + n)) = v;
}

// ---------------- pass 2: dense levels (0..4) + merge -----------------------
__global__ __launch_bounds__(256) void dense_merge_kernel(
    const float* __restrict__ x,
    const float* __restrict__ params,
    const _Float16* __restrict__ ws,   // [N_HASHED][N] half2
    float* __restrict__ out,
    int N)
{
    constexpr int      DRES[5] = {16, 23, 32, 46, 64};
    constexpr unsigned DOFF[5] = {0u, 4096u, 16264u, 49032u, 146368u};

    const int n = blockIdx.x * blockDim.x + threadIdx.x;
    if (n >= N) return;

    const float px = x[3 * n + 0];
    const float py = x[3 * n + 1];
    const float pz = x[3 * n + 2];

    float res[2 * N_LEVELS];

#pragma unroll
    for (int l = 0; l < 5; ++l) {
        const int r = DRES[l];
        float wx[2], wy[2], wz[2];
        unsigned ix, iy, iz;
        trilinear_setup(px, r, wx, &ix);
        trilinear_setup(py, r, wy, &iy);
        trilinear_setup(pz, r, wz, &iz);

        const float* __restrict__ tabf = params + 2u * (size_t)DOFF[l];
        const unsigned rr = (unsigned)(r * r);
        const unsigned base = ix + iy * (unsigned)r + iz * rr;

        float s0 = 0.0f, s1 = 0.0f;
#pragma unroll
        for (int p = 0; p < 4; ++p) {
            const unsigned dy = p & 1, dz = (p >> 1) & 1;
            const unsigned idx = base + dy * (unsigned)r + dz * rr;  // dx=0; dx=1 is idx+1
            const f4a8 q = *(const f4a8*)(tabf + 2u * idx);          // {c0.x,c0.y,c1.x,c1.y}
            const float wyz = wy[dy] * wz[dz];
            const float wc0 = wx[0] * wyz;
            const float wc1 = wx[1] * wyz;
            s0 = fmaf(wc0, q.x, s0);
            s1 = fmaf(wc0, q.y, s1);
            s0 = fmaf(wc1, q.z, s0);
            s1 = fmaf(wc1, q.w, s1);
        }
        res[2 * l + 0] = s0;
        res[2 * l + 1] = s1;
    }

#pragma unroll
    for (int li = 0; li < N_HASHED; ++li) {
        const h2v f = *(const h2v*)(ws + 2u * ((size_t)li * N + n));  // coalesced 4B
        res[2 * (5 + li) + 0] = (float)f.x;
        res[2 * (5 + li) + 1] = (float)f.y;
    }

    float* __restrict__ ob = out + (size_t)n * 24;
#pragma unroll
    for (int k = 0; k < 6; ++k) {
        f4v v;
        v.x = res[4 * k + 0];
        v.y = res[4 * k + 1];
        v.z = res[4 * k + 2];
        v.w = res[4 * k + 3];
        __builtin_nontemporal_store(v, (f4v*)(ob + 4 * k));  // out: write-once stream
    }
}

// ---------------- fallback: fused single kernel -----------------------------
__global__ __launch_bounds__(256) void grid_encode_fused_kernel(
    const float* __restrict__ x,
    const float* __restrict__ params,
    float* __restrict__ out,
    int N)
{
    int n = blockIdx.x * blockDim.x + threadIdx.x;
    if (n >= N) return;

    const float px = x[3 * n + 0];
    const float py = x[3 * n + 1];
    const float pz = x[3 * n + 2];

    constexpr int   RES[N_LEVELS]    = {16, 23, 32, 46, 64, 92, 128, 184, 256, 368, 512, 736};
    constexpr unsigned OFF[N_LEVELS] = {0u, 4096u, 16264u, 49032u, 146368u, 408512u,
                                        932800u, 1457088u, 1981376u, 2505664u, 3029952u, 3554240u};
    constexpr unsigned HASH_MASK = 524287u;
    constexpr unsigned P1 = 2654435761u;
    constexpr unsigned P2 = 805459861u;

    float res[2 * N_LEVELS];

#pragma unroll
    for (int l = 0; l < N_LEVELS; ++l) {
        const int r = RES[l];
        float wx[2], wy[2], wz[2];
        unsigned ix, iy, iz;
        trilinear_setup(px, r, wx, &ix);
        trilinear_setup(py, r, wy, &iy);
        trilinear_setup(pz, r, wz, &iz);

        const float2* __restrict__ tab = (const float2*)params + OFF[l];
        float s0 = 0.0f, s1 = 0.0f;

        const bool dense = ((long long)r * r * r) <= (long long)524288;
        if (dense) {
            const unsigned rr = (unsigned)(r * r);
            const unsigned base = ix + iy * (unsigned)r + iz * rr;
#pragma unroll
            for (int c = 0; c < 8; ++c) {
                const unsigned dx = c & 1, dy = (c >> 1) & 1, dz = (c >> 2) & 1;
                const unsigned idx = base + dx + dy * (unsigned)r + dz * rr;
                float2 f = tab[idx];
                float wc = (wx[dx] * wy[dy]) * wz[dz];
                s0 = fmaf(wc, f.x, s0);
                s1 = fmaf(wc, f.y, s1);
            }
        } else {
            const unsigned hx[2] = {ix, ix + 1u};
            const unsigned hy[2] = {iy * P1, (iy + 1u) * P1};
            const unsigned hz[2] = {iz * P2, (iz + 1u) * P2};
#pragma unroll
            for (int c = 0; c < 8; ++c) {
                const unsigned dx = c & 1, dy = (c >> 1) & 1, dz = (c >> 2) & 1;
                const unsigned idx = (hx[dx] ^ hy[dy] ^ hz[dz]) & HASH_MASK;
                float2 f = tab[idx];
                float wc = (wx[dx] * wy[dy]) * wz[dz];
                s0 = fmaf(wc, f.x, s0);
                s1 = fmaf(wc, f.y, s1);
            }
        }
        res[2 * l + 0] = s0;
        res[2 * l + 1] = s1;
    }

    float4* __restrict__ o4 = (float4*)(out + (size_t)n * 24);
#pragma unroll
    for (int k = 0; k < 6; ++k) {
        float4 v;
        v.x = res[4 * k + 0];
        v.y = res[4 * k + 1];
        v.z = res[4 * k + 2];
        v.w = res[4 * k + 3];
        o4[k] = v;
    }
}

extern "C" void kernel_launch(void* const* d_in, const int* in_sizes, int n_in,
                              void* d_out, int out_size, void* d_ws, size_t ws_size,
                              hipStream_t stream) {
    const float* x      = (const float*)d_in[0];
    const float* params = (const float*)d_in[1];
    float* out          = (float*)d_out;

    const int N = in_sizes[0] / 3;  // 1<<20
    const int block = 256;
    const int gx = (N + block - 1) / block;

    const size_t ws_needed = (size_t)N_HASHED * (size_t)N * sizeof(_Float16) * 2;  // 28 MB

    if (ws_size >= ws_needed) {
        _Float16* ws = (_Float16*)d_ws;
        dim3 grid1(gx, N_HASHED, 1);
        hashed_levels_kernel<<<grid1, block, 0, stream>>>(x, params, ws, N);
        dense_merge_kernel<<<gx, block, 0, stream>>>(x, params, ws, out, N);
    } else {
        grid_encode_fused_kernel<<<gx, block, 0, stream>>>(x, params, out, N);
    }
}

// Round 10
// 233.231 us; speedup vs baseline: 1.5469x; 1.3714x over previous
//
#include <hip/hip_runtime.h>

// instant-NGP hash-grid encoder, 12 levels, F=2, N = 1<<20 points.
// Levels 0-4 dense (R^3 <= 2^19), levels 5-11 hashed (table = 2^19 entries).
//
// R2: per-hashed-level passes (gridDim.y) + ws staging + merge kernel.
// R4/R6: corner pairing (dx=0/1 adjacent -> one paired load) — win.
// R5/R9 lesson: NO non-temporal hints ANYWHERE. NT on re-read buffers (ws/x)
//     poisons the consumer; NT on the write-once out stream also cost ~40 us
//     (breaks L2 write-combining). All plain loads/stores.
// R7 lesson: 2 pts/thread hurt. R8 lesson: branch-free 8-load path hurt;
//     the hashed pass is line-request bound — divergent pairing is minimal.
// R9: fp16 ws staging (|v|<=1e-4, quant err ~3e-8 << 2e-6 threshold) — kept.
// R10: fp16 PARAM TABLES. Convert params to fp16 in d_ws once per launch
//     (~10 us). Hashed tables drop 4MB->2MB => fully L2-resident per XCD
//     (today the 4MB table exactly fills L2 and the x/ws streams evict it).
//     Dense tables 3.3MB->1.65MB. Quant err ~6e-8/corner, total ~1.5e-7.

#define N_LEVELS 12
#define N_HASHED 7

typedef float    f4v  __attribute__((ext_vector_type(4)));
typedef _Float16 h2a4 __attribute__((ext_vector_type(2), aligned(4)));
typedef _Float16 h4a4 __attribute__((ext_vector_type(4), aligned(4)));
typedef _Float16 h4a8 __attribute__((ext_vector_type(4), aligned(8)));
typedef _Float16 h2v  __attribute__((ext_vector_type(2)));

__device__ __forceinline__ void trilinear_setup(float p, int r, float* w, unsigned* i0)
{
    float f  = p * (float)(r - 1);
    float f0 = fminf(fmaxf(floorf(f), 0.0f), (float)(r - 2));
    float w1 = f - f0;
    w[0] = 1.0f - w1;
    w[1] = w1;
    *i0 = (unsigned)f0;
}

// ---------------- pass 0: convert params fp32 -> fp16 -----------------------
__global__ __launch_bounds__(256) void convert_params_kernel(
    const float* __restrict__ src,
    _Float16* __restrict__ dst,
    int total_floats)   // 8157056, divisible by 4
{
    const int t = blockIdx.x * blockDim.x + threadIdx.x;
    const int i = 4 * t;
    if (i >= total_floats) return;
    const f4v v = *(const f4v*)(src + i);
    h4a8 h;
    h.x = (_Float16)v.x;
    h.y = (_Float16)v.y;
    h.z = (_Float16)v.z;
    h.w = (_Float16)v.w;
    *(h4a8*)(dst + i) = h;
}

// ---------------- pass 1: hashed levels (5..11), one level per blockIdx.y ----
__global__ __launch_bounds__(256) void hashed_levels_kernel(
    const float* __restrict__ x,
    const _Float16* __restrict__ params_h,
    _Float16* __restrict__ ws,   // [N_HASHED][N] half2
    int N)
{
    constexpr int      HRES[N_HASHED] = {92, 128, 184, 256, 368, 512, 736};
    constexpr unsigned HOFF[N_HASHED] = {408512u, 932800u, 1457088u, 1981376u,
                                         2505664u, 3029952u, 3554240u};
    constexpr unsigned HASH_MASK = 524287u;   // 2^19 - 1
    constexpr unsigned P1 = 2654435761u;
    constexpr unsigned P2 = 805459861u;

    const int n = blockIdx.x * blockDim.x + threadIdx.x;
    if (n >= N) return;
    const int li = blockIdx.y;          // 0..6 -> level 5+li

    const float px = x[3 * n + 0];
    const float py = x[3 * n + 1];
    const float pz = x[3 * n + 2];

    const int r = HRES[li];
    float wx[2], wy[2], wz[2];
    unsigned ix, iy, iz;
    trilinear_setup(px, r, wx, &ix);
    trilinear_setup(py, r, wy, &iy);
    trilinear_setup(pz, r, wz, &iz);

    const _Float16* __restrict__ tabh = params_h + 2u * (size_t)HOFF[li];

    const unsigned hy[2] = {iy * P1, (iy + 1u) * P1};
    const unsigned hz[2] = {iz * P2, (iz + 1u) * P2};

    float s0 = 0.0f, s1 = 0.0f;

    if ((ix & 1u) == 0u) {
        // even ix: corner pair (dx=0,dx=1) = {a, a^1} -> one 8B-aligned load
#pragma unroll
        for (int p = 0; p < 4; ++p) {
            const unsigned dy = p & 1, dz = (p >> 1) & 1;
            const unsigned h = hy[dy] ^ hz[dz];
            const unsigned a = (ix ^ h) & HASH_MASK;      // corner dx=0
            const unsigned sw = a & 1u;                   // 1 -> pair stored (c1,c0)
            const h4a8 q = *(const h4a8*)(tabh + 2u * (a & ~1u));
            const float qx = (float)q.x, qy = (float)q.y;
            const float qz = (float)q.z, qw = (float)q.w;
            const float f0x = sw ? qz : qx;
            const float f0y = sw ? qw : qy;
            const float f1x = sw ? qx : qz;
            const float f1y = sw ? qy : qw;
            const float wyz = wy[dy] * wz[dz];
            const float wc0 = wx[0] * wyz;
            const float wc1 = wx[1] * wyz;
            s0 = fmaf(wc0, f0x, s0);
            s1 = fmaf(wc0, f0y, s1);
            s0 = fmaf(wc1, f1x, s0);
            s1 = fmaf(wc1, f1y, s1);
        }
    } else {
        const unsigned hx[2] = {ix, ix + 1u};
#pragma unroll
        for (int c = 0; c < 8; ++c) {
            const unsigned dx = c & 1, dy = (c >> 1) & 1, dz = (c >> 2) & 1;
            const unsigned idx = (hx[dx] ^ hy[dy] ^ hz[dz]) & HASH_MASK;
            const h2a4 f = *(const h2a4*)(tabh + 2u * idx);
            const float wc = (wx[dx] * wy[dy]) * wz[dz];
            s0 = fmaf(wc, (float)f.x, s0);
            s1 = fmaf(wc, (float)f.y, s1);
        }
    }

    h2v v;
    v.x = (_Float16)s0;
    v.y = (_Float16)s1;
    *(h2v*)(ws + 2u * ((size_t)li * N + n)) = v;
}

// ---------------- pass 2: dense levels (0..4) + merge -----------------------
__global__ __launch_bounds__(256) void dense_merge_kernel(
    const float* __restrict__ x,
    const _Float16* __restrict__ params_h,
    const _Float16* __restrict__ ws,   // [N_HASHED][N] half2
    float* __restrict__ out,
    int N)
{
    constexpr int      DRES[5] = {16, 23, 32, 46, 64};
    constexpr unsigned DOFF[5] = {0u, 4096u, 16264u, 49032u, 146368u};

    const int n = blockIdx.x * blockDim.x + threadIdx.x;
    if (n >= N) return;

    const float px = x[3 * n + 0];
    const float py = x[3 * n + 1];
    const float pz = x[3 * n + 2];

    float res[2 * N_LEVELS];

#pragma unroll
    for (int l = 0; l < 5; ++l) {
        const int r = DRES[l];
        float wx[2], wy[2], wz[2];
        unsigned ix, iy, iz;
        trilinear_setup(px, r, wx, &ix);
        trilinear_setup(py, r, wy, &iy);
        trilinear_setup(pz, r, wz, &iz);

        const _Float16* __restrict__ tabh = params_h + 2u * (size_t)DOFF[l];
        const unsigned rr = (unsigned)(r * r);
        const unsigned base = ix + iy * (unsigned)r + iz * rr;

        float s0 = 0.0f, s1 = 0.0f;
#pragma unroll
        for (int p = 0; p < 4; ++p) {
            const unsigned dy = p & 1, dz = (p >> 1) & 1;
            const unsigned idx = base + dy * (unsigned)r + dz * rr;  // dx=0; dx=1 is idx+1
            const h4a4 q = *(const h4a4*)(tabh + 2u * idx);          // {c0.x,c0.y,c1.x,c1.y}
            const float wyz = wy[dy] * wz[dz];
            const float wc0 = wx[0] * wyz;
            const float wc1 = wx[1] * wyz;
            s0 = fmaf(wc0, (float)q.x, s0);
            s1 = fmaf(wc0, (float)q.y, s1);
            s0 = fmaf(wc1, (float)q.z, s0);
            s1 = fmaf(wc1, (float)q.w, s1);
        }
        res[2 * l + 0] = s0;
        res[2 * l + 1] = s1;
    }

#pragma unroll
    for (int li = 0; li < N_HASHED; ++li) {
        const h2a4 f = *(const h2a4*)(ws + 2u * ((size_t)li * N + n));  // coalesced 4B
        res[2 * (5 + li) + 0] = (float)f.x;
        res[2 * (5 + li) + 1] = (float)f.y;
    }

    float4* __restrict__ o4 = (float4*)(out + (size_t)n * 24);
#pragma unroll
    for (int k = 0; k < 6; ++k) {
        float4 v;
        v.x = res[4 * k + 0];
        v.y = res[4 * k + 1];
        v.z = res[4 * k + 2];
        v.w = res[4 * k + 3];
        o4[k] = v;
    }
}

// ---------------- fallback: fused single kernel (fp32 tables) ---------------
__global__ __launch_bounds__(256) void grid_encode_fused_kernel(
    const float* __restrict__ x,
    const float* __restrict__ params,
    float* __restrict__ out,
    int N)
{
    int n = blockIdx.x * blockDim.x + threadIdx.x;
    if (n >= N) return;

    const float px = x[3 * n + 0];
    const float py = x[3 * n + 1];
    const float pz = x[3 * n + 2];

    constexpr int   RES[N_LEVELS]    = {16, 23, 32, 46, 64, 92, 128, 184, 256, 368, 512, 736};
    constexpr unsigned OFF[N_LEVELS] = {0u, 4096u, 16264u, 49032u, 146368u, 408512u,
                                        932800u, 1457088u, 1981376u, 2505664u, 3029952u, 3554240u};
    constexpr unsigned HASH_MASK = 524287u;
    constexpr unsigned P1 = 2654435761u;
    constexpr unsigned P2 = 805459861u;

    float res[2 * N_LEVELS];

#pragma unroll
    for (int l = 0; l < N_LEVELS; ++l) {
        const int r = RES[l];
        float wx[2], wy[2], wz[2];
        unsigned ix, iy, iz;
        trilinear_setup(px, r, wx, &ix);
        trilinear_setup(py, r, wy, &iy);
        trilinear_setup(pz, r, wz, &iz);

        const float2* __restrict__ tab = (const float2*)params + OFF[l];
        float s0 = 0.0f, s1 = 0.0f;

        const bool dense = ((long long)r * r * r) <= (long long)524288;
        if (dense) {
            const unsigned rr = (unsigned)(r * r);
            const unsigned base = ix + iy * (unsigned)r + iz * rr;
#pragma unroll
            for (int c = 0; c < 8; ++c) {
                const unsigned dx = c & 1, dy = (c >> 1) & 1, dz = (c >> 2) & 1;
                const unsigned idx = base + dx + dy * (unsigned)r + dz * rr;
                float2 f = tab[idx];
                float wc = (wx[dx] * wy[dy]) * wz[dz];
                s0 = fmaf(wc, f.x, s0);
                s1 = fmaf(wc, f.y, s1);
            }
        } else {
            const unsigned hx[2] = {ix, ix + 1u};
            const unsigned hy[2] = {iy * P1, (iy + 1u) * P1};
            const unsigned hz[2] = {iz * P2, (iz + 1u) * P2};
#pragma unroll
            for (int c = 0; c < 8; ++c) {
                const unsigned dx = c & 1, dy = (c >> 1) & 1, dz = (c >> 2) & 1;
                const unsigned idx = (hx[dx] ^ hy[dy] ^ hz[dz]) & HASH_MASK;
                float2 f = tab[idx];
                float wc = (wx[dx] * wy[dy]) * wz[dz];
                s0 = fmaf(wc, f.x, s0);
                s1 = fmaf(wc, f.y, s1);
            }
        }
        res[2 * l + 0] = s0;
        res[2 * l + 1] = s1;
    }

    float4* __restrict__ o4 = (float4*)(out + (size_t)n * 24);
#pragma unroll
    for (int k = 0; k < 6; ++k) {
        float4 v;
        v.x = res[4 * k + 0];
        v.y = res[4 * k + 1];
        v.z = res[4 * k + 2];
        v.w = res[4 * k + 3];
        o4[k] = v;
    }
}

extern "C" void kernel_launch(void* const* d_in, const int* in_sizes, int n_in,
                              void* d_out, int out_size, void* d_ws, size_t ws_size,
                              hipStream_t stream) {
    const float* x      = (const float*)d_in[0];
    const float* params = (const float*)d_in[1];
    float* out          = (float*)d_out;

    const int N = in_sizes[0] / 3;            // 1<<20
    const int total_floats = in_sizes[1];     // 8157056 (params count * 2)
    const int block = 256;
    const int gx = (N + block - 1) / block;

    // d_ws layout: [params_h: total_floats * 2B][ws: N_HASHED * N * 4B]
    const size_t params_h_bytes = (size_t)total_floats * sizeof(_Float16);
    const size_t ws_bytes       = (size_t)N_HASHED * (size_t)N * sizeof(_Float16) * 2;
    const size_t ws_needed      = params_h_bytes + ws_bytes;   // ~45.7 MB

    if (ws_size >= ws_needed) {
        _Float16* params_h = (_Float16*)d_ws;
        _Float16* ws       = (_Float16*)((char*)d_ws + params_h_bytes);

        const int gconv = (total_floats / 4 + block - 1) / block;
        convert_params_kernel<<<gconv, block, 0, stream>>>(params, params_h, total_floats);

        dim3 grid1(gx, N_HASHED, 1);
        hashed_levels_kernel<<<grid1, block, 0, stream>>>(x, params_h, ws, N);
        dense_merge_kernel<<<gx, block, 0, stream>>>(x, params_h, ws, out, N);
    } else {
        grid_encode_fused_kernel<<<gx, block, 0, stream>>>(x, params, out, N);
    }
}

// Round 11
// 232.067 us; speedup vs baseline: 1.5547x; 1.0050x over previous
//
#include <hip/hip_runtime.h>

// instant-NGP hash-grid encoder, 12 levels, F=2, N = 1<<20 points.
// Levels 0-4 dense (R^3 <= 2^19), levels 5-11 hashed (table = 2^19 entries).
//
// R2: per-hashed-level passes (gridDim.y) + ws staging + merge kernel.
// R4/R6: corner pairing (dx=0/1 adjacent -> one paired load) — win.
// R5/R9 lesson: NO non-temporal hints ANYWHERE (hurt both re-read and
//     write-once streams). R7: 2 pts/thread hurt. R8: branch-free path hurt.
// R9: fp16 ws staging. R10: fp16 param tables (conv pass ~10us) — hashed
//     tables 2MB => L2-resident, FETCH 280->98MB, hashed 177->143us.
// R11: margin squeeze. (a) hashed at block=64 (1 wave/block) to fill all 32
//     wave slots/CU (occupancy was 83% at 4-wave blocks) — the pass sits at
//     ~96% of the request-throughput/latency floor (~137us), more resident
//     waves = more outstanding requests. (b) merge issues the 7 coalesced ws
//     reads BEFORE the dense gathers so all loads share one latency window.

#define N_LEVELS 12
#define N_HASHED 7

typedef float    f4v  __attribute__((ext_vector_type(4)));
typedef _Float16 h2a4 __attribute__((ext_vector_type(2), aligned(4)));
typedef _Float16 h4a4 __attribute__((ext_vector_type(4), aligned(4)));
typedef _Float16 h4a8 __attribute__((ext_vector_type(4), aligned(8)));
typedef _Float16 h2v  __attribute__((ext_vector_type(2)));

__device__ __forceinline__ void trilinear_setup(float p, int r, float* w, unsigned* i0)
{
    float f  = p * (float)(r - 1);
    float f0 = fminf(fmaxf(floorf(f), 0.0f), (float)(r - 2));
    float w1 = f - f0;
    w[0] = 1.0f - w1;
    w[1] = w1;
    *i0 = (unsigned)f0;
}

// ---------------- pass 0: convert params fp32 -> fp16 -----------------------
__global__ __launch_bounds__(256) void convert_params_kernel(
    const float* __restrict__ src,
    _Float16* __restrict__ dst,
    int total_floats)   // divisible by 4
{
    const int t = blockIdx.x * blockDim.x + threadIdx.x;
    const int i = 4 * t;
    if (i >= total_floats) return;
    const f4v v = *(const f4v*)(src + i);
    h4a8 h;
    h.x = (_Float16)v.x;
    h.y = (_Float16)v.y;
    h.z = (_Float16)v.z;
    h.w = (_Float16)v.w;
    *(h4a8*)(dst + i) = h;
}

// ---------------- pass 1: hashed levels (5..11), one level per blockIdx.y ----
// block = 64 (1 wave) for max resident-wave count.
__global__ __launch_bounds__(64) void hashed_levels_kernel(
    const float* __restrict__ x,
    const _Float16* __restrict__ params_h,
    _Float16* __restrict__ ws,   // [N_HASHED][N] half2
    int N)
{
    constexpr int      HRES[N_HASHED] = {92, 128, 184, 256, 368, 512, 736};
    constexpr unsigned HOFF[N_HASHED] = {408512u, 932800u, 1457088u, 1981376u,
                                         2505664u, 3029952u, 3554240u};
    constexpr unsigned HASH_MASK = 524287u;   // 2^19 - 1
    constexpr unsigned P1 = 2654435761u;
    constexpr unsigned P2 = 805459861u;

    const int n = blockIdx.x * blockDim.x + threadIdx.x;
    if (n >= N) return;
    const int li = blockIdx.y;          // 0..6 -> level 5+li

    const float px = x[3 * n + 0];
    const float py = x[3 * n + 1];
    const float pz = x[3 * n + 2];

    const int r = HRES[li];
    float wx[2], wy[2], wz[2];
    unsigned ix, iy, iz;
    trilinear_setup(px, r, wx, &ix);
    trilinear_setup(py, r, wy, &iy);
    trilinear_setup(pz, r, wz, &iz);

    const _Float16* __restrict__ tabh = params_h + 2u * (size_t)HOFF[li];

    const unsigned hy[2] = {iy * P1, (iy + 1u) * P1};
    const unsigned hz[2] = {iz * P2, (iz + 1u) * P2};

    float s0 = 0.0f, s1 = 0.0f;

    if ((ix & 1u) == 0u) {
        // even ix: corner pair (dx=0,dx=1) = {a, a^1} -> one 8B-aligned load
#pragma unroll
        for (int p = 0; p < 4; ++p) {
            const unsigned dy = p & 1, dz = (p >> 1) & 1;
            const unsigned h = hy[dy] ^ hz[dz];
            const unsigned a = (ix ^ h) & HASH_MASK;      // corner dx=0
            const unsigned sw = a & 1u;                   // 1 -> pair stored (c1,c0)
            const h4a8 q = *(const h4a8*)(tabh + 2u * (a & ~1u));
            const float qx = (float)q.x, qy = (float)q.y;
            const float qz = (float)q.z, qw = (float)q.w;
            const float f0x = sw ? qz : qx;
            const float f0y = sw ? qw : qy;
            const float f1x = sw ? qx : qz;
            const float f1y = sw ? qy : qw;
            const float wyz = wy[dy] * wz[dz];
            const float wc0 = wx[0] * wyz;
            const float wc1 = wx[1] * wyz;
            s0 = fmaf(wc0, f0x, s0);
            s1 = fmaf(wc0, f0y, s1);
            s0 = fmaf(wc1, f1x, s0);
            s1 = fmaf(wc1, f1y, s1);
        }
    } else {
        const unsigned hx[2] = {ix, ix + 1u};
#pragma unroll
        for (int c = 0; c < 8; ++c) {
            const unsigned dx = c & 1, dy = (c >> 1) & 1, dz = (c >> 2) & 1;
            const unsigned idx = (hx[dx] ^ hy[dy] ^ hz[dz]) & HASH_MASK;
            const h2a4 f = *(const h2a4*)(tabh + 2u * idx);
            const float wc = (wx[dx] * wy[dy]) * wz[dz];
            s0 = fmaf(wc, (float)f.x, s0);
            s1 = fmaf(wc, (float)f.y, s1);
        }
    }

    h2v v;
    v.x = (_Float16)s0;
    v.y = (_Float16)s1;
    *(h2v*)(ws + 2u * ((size_t)li * N + n)) = v;
}

// ---------------- pass 2: dense levels (0..4) + merge -----------------------
__global__ __launch_bounds__(256) void dense_merge_kernel(
    const float* __restrict__ x,
    const _Float16* __restrict__ params_h,
    const _Float16* __restrict__ ws,   // [N_HASHED][N] half2
    float* __restrict__ out,
    int N)
{
    constexpr int      DRES[5] = {16, 23, 32, 46, 64};
    constexpr unsigned DOFF[5] = {0u, 4096u, 16264u, 49032u, 146368u};

    const int n = blockIdx.x * blockDim.x + threadIdx.x;
    if (n >= N) return;

    const float px = x[3 * n + 0];
    const float py = x[3 * n + 1];
    const float pz = x[3 * n + 2];

    // Issue the 7 coalesced ws reads first — they share the latency window
    // with the dense gathers below.
    h2a4 wsf[N_HASHED];
#pragma unroll
    for (int li = 0; li < N_HASHED; ++li) {
        wsf[li] = *(const h2a4*)(ws + 2u * ((size_t)li * N + n));
    }

    float res[2 * N_LEVELS];

#pragma unroll
    for (int l = 0; l < 5; ++l) {
        const int r = DRES[l];
        float wx[2], wy[2], wz[2];
        unsigned ix, iy, iz;
        trilinear_setup(px, r, wx, &ix);
        trilinear_setup(py, r, wy, &iy);
        trilinear_setup(pz, r, wz, &iz);

        const _Float16* __restrict__ tabh = params_h + 2u * (size_t)DOFF[l];
        const unsigned rr = (unsigned)(r * r);
        const unsigned base = ix + iy * (unsigned)r + iz * rr;

        float s0 = 0.0f, s1 = 0.0f;
#pragma unroll
        for (int p = 0; p < 4; ++p) {
            const unsigned dy = p & 1, dz = (p >> 1) & 1;
            const unsigned idx = base + dy * (unsigned)r + dz * rr;  // dx=0; dx=1 is idx+1
            const h4a4 q = *(const h4a4*)(tabh + 2u * idx);          // {c0.x,c0.y,c1.x,c1.y}
            const float wyz = wy[dy] * wz[dz];
            const float wc0 = wx[0] * wyz;
            const float wc1 = wx[1] * wyz;
            s0 = fmaf(wc0, (float)q.x, s0);
            s1 = fmaf(wc0, (float)q.y, s1);
            s0 = fmaf(wc1, (float)q.z, s0);
            s1 = fmaf(wc1, (float)q.w, s1);
        }
        res[2 * l + 0] = s0;
        res[2 * l + 1] = s1;
    }

#pragma unroll
    for (int li = 0; li < N_HASHED; ++li) {
        res[2 * (5 + li) + 0] = (float)wsf[li].x;
        res[2 * (5 + li) + 1] = (float)wsf[li].y;
    }

    float4* __restrict__ o4 = (float4*)(out + (size_t)n * 24);
#pragma unroll
    for (int k = 0; k < 6; ++k) {
        float4 v;
        v.x = res[4 * k + 0];
        v.y = res[4 * k + 1];
        v.z = res[4 * k + 2];
        v.w = res[4 * k + 3];
        o4[k] = v;
    }
}

// ---------------- fallback: fused single kernel (fp32 tables) ---------------
__global__ __launch_bounds__(256) void grid_encode_fused_kernel(
    const float* __restrict__ x,
    const float* __restrict__ params,
    float* __restrict__ out,
    int N)
{
    int n = blockIdx.x * blockDim.x + threadIdx.x;
    if (n >= N) return;

    const float px = x[3 * n + 0];
    const float py = x[3 * n + 1];
    const float pz = x[3 * n + 2];

    constexpr int   RES[N_LEVELS]    = {16, 23, 32, 46, 64, 92, 128, 184, 256, 368, 512, 736};
    constexpr unsigned OFF[N_LEVELS] = {0u, 4096u, 16264u, 49032u, 146368u, 408512u,
                                        932800u, 1457088u, 1981376u, 2505664u, 3029952u, 3554240u};
    constexpr unsigned HASH_MASK = 524287u;
    constexpr unsigned P1 = 2654435761u;
    constexpr unsigned P2 = 805459861u;

    float res[2 * N_LEVELS];

#pragma unroll
    for (int l = 0; l < N_LEVELS; ++l) {
        const int r = RES[l];
        float wx[2], wy[2], wz[2];
        unsigned ix, iy, iz;
        trilinear_setup(px, r, wx, &ix);
        trilinear_setup(py, r, wy, &iy);
        trilinear_setup(pz, r, wz, &iz);

        const float2* __restrict__ tab = (const float2*)params + OFF[l];
        float s0 = 0.0f, s1 = 0.0f;

        const bool dense = ((long long)r * r * r) <= (long long)524288;
        if (dense) {
            const unsigned rr = (unsigned)(r * r);
            const unsigned base = ix + iy * (unsigned)r + iz * rr;
#pragma unroll
            for (int c = 0; c < 8; ++c) {
                const unsigned dx = c & 1, dy = (c >> 1) & 1, dz = (c >> 2) & 1;
                const unsigned idx = base + dx + dy * (unsigned)r + dz * rr;
                float2 f = tab[idx];
                float wc = (wx[dx] * wy[dy]) * wz[dz];
                s0 = fmaf(wc, f.x, s0);
                s1 = fmaf(wc, f.y, s1);
            }
        } else {
            const unsigned hx[2] = {ix, ix + 1u};
            const unsigned hy[2] = {iy * P1, (iy + 1u) * P1};
            const unsigned hz[2] = {iz * P2, (iz + 1u) * P2};
#pragma unroll
            for (int c = 0; c < 8; ++c) {
                const unsigned dx = c & 1, dy = (c >> 1) & 1, dz = (c >> 2) & 1;
                const unsigned idx = (hx[dx] ^ hy[dy] ^ hz[dz]) & HASH_MASK;
                float2 f = tab[idx];
                float wc = (wx[dx] * wy[dy]) * wz[dz];
                s0 = fmaf(wc, f.x, s0);
                s1 = fmaf(wc, f.y, s1);
            }
        }
        res[2 * l + 0] = s0;
        res[2 * l + 1] = s1;
    }

    float4* __restrict__ o4 = (float4*)(out + (size_t)n * 24);
#pragma unroll
    for (int k = 0; k < 6; ++k) {
        float4 v;
        v.x = res[4 * k + 0];
        v.y = res[4 * k + 1];
        v.z = res[4 * k + 2];
        v.w = res[4 * k + 3];
        o4[k] = v;
    }
}

extern "C" void kernel_launch(void* const* d_in, const int* in_sizes, int n_in,
                              void* d_out, int out_size, void* d_ws, size_t ws_size,
                              hipStream_t stream) {
    const float* x      = (const float*)d_in[0];
    const float* params = (const float*)d_in[1];
    float* out          = (float*)d_out;

    const int N = in_sizes[0] / 3;            // 1<<20
    const int total_floats = in_sizes[1];     // 8157056 (params count * 2)
    const int block = 256;
    const int gx = (N + block - 1) / block;

    // d_ws layout: [params_h: total_floats * 2B][ws: N_HASHED * N * 4B]
    const size_t params_h_bytes = (size_t)total_floats * sizeof(_Float16);
    const size_t ws_bytes       = (size_t)N_HASHED * (size_t)N * sizeof(_Float16) * 2;
    const size_t ws_needed      = params_h_bytes + ws_bytes;   // ~45.7 MB

    if (ws_size >= ws_needed) {
        _Float16* params_h = (_Float16*)d_ws;
        _Float16* ws       = (_Float16*)((char*)d_ws + params_h_bytes);

        const int gconv = (total_floats / 4 + block - 1) / block;
        convert_params_kernel<<<gconv, block, 0, stream>>>(params, params_h, total_floats);

        const int gx64 = (N + 63) / 64;
        dim3 grid1(gx64, N_HASHED, 1);
        hashed_levels_kernel<<<grid1, 64, 0, stream>>>(x, params_h, ws, N);
        dense_merge_kernel<<<gx, block, 0, stream>>>(x, params_h, ws, out, N);
    } else {
        grid_encode_fused_kernel<<<gx, block, 0, stream>>>(x, params, out, N);
    }
}